// Round 13
// baseline (210.581 us; speedup 1.0000x reference)
//
#include <hip/hip_runtime.h>

// B=1024, S=256, D=128, H1=256, H2=64.
// h1_pre[s,h] = bias1[b,h] + sum_d keys[s,d] * Weff_b[d,h]   (K=128 GEMM)
//   Weff_b[d,h] = (W1b - W1c)[d,h] + q_b[d] * W1d[d,h]
//   bias1[b,h]  = b1[h] + q_b @ (W1a + W1c)
// R13 = R12 + fused flash-style epilogue:
//   scores are bounded (|score| <~ 0.6) => softmax WITHOUT max-subtract is safe.
//   scores[] holds e = exp(score) (masked 0); out_acc accumulated per-thread from
//   the LDS-staged keys tile (kbuf TRIPLE-buffered so ACCUM(t) in iter t+1 never
//   races STORE(t+3) in iter t+2); final out = red(out_acc)/sum(e).
//   Deletes: 128MB epilogue keys re-read, epilogue FMA pass, softmax max phase.
//   Also: full unroll of tile loop (folds %3 bases + swz into immediates),
//   GEMM2 acc chain split 8 -> 2x4.

typedef unsigned short u16;
typedef unsigned int u32;
typedef short bf16x8 __attribute__((ext_vector_type(8)));
typedef float f32x4 __attribute__((ext_vector_type(4)));

#define NBATCH 1024
#define SLEN 256
#define DD 128
#define NH1 256
#define NH2 64

// ws layout (bytes)
#define WS_WBCT  0         // [256h][128k] bf16  (W1b - W1c)^T
#define WS_WDT   65536     // [256h][128k] bf16  W1d^T
#define WS_W2T   131072    // [64o][256h]  bf16  W2^T
#define WS_WDS   163840    // 65 f32 (Wd[64], bd)
#define WS_WSUM  165888    // [128d][256h] f32   W1a + W1c
#define WS_BIAS1 296960    // [1024][256] f32

// LDS map (main kernel)
#define L_KBUF   0         // [3][32][128] bf16, swzk (3 x 8KB; bases 8K-aligned, swzk-safe)
#define L_H1     24576     // h1 bf16 [32 s][256 h] = [32][512B], swz (base bits>=13, swz-safe)
#define L_SCORES 40960     // f32[256]: e-values (exp(score), masked 0)
#define L_BIAS   41984     // f32[256]
#define L_B2     43008     // f32[64]
#define L_WD     43264     // f32[66] (pad)
#define L_WPART  43536     // f32[4][32]
#define L_RED4   44048     // f32[16]
#define L_SIZE   44112

__device__ __forceinline__ u16 f2bf_rne(float f){
  union { float f; unsigned u; } v; v.f = f;
  unsigned r = v.u + 0x7fffu + ((v.u >> 16) & 1u);
  return (u16)(r >> 16);
}
__device__ __forceinline__ u32 pack_trunc(float a, float b){
  return (__float_as_uint(a) >> 16) | (__float_as_uint(b) & 0xffff0000u);
}
__device__ __forceinline__ float b2fl(short s){
  return __uint_as_float(((u32)(u16)s) << 16);
}
__device__ __forceinline__ int swz(int byte){    // h1: 512B rows
  return byte ^ (((byte >> 9) & 7) << 4);
}
__device__ __forceinline__ int swzk(int byte){   // kbuf: 256B rows
  return byte ^ (((byte >> 8) & 7) << 4);
}
__device__ __forceinline__ float fsigmoid(float x){
  return __builtin_amdgcn_rcpf(1.f + __expf(-x));
}
__device__ __forceinline__ void barrier_lds(){
  asm volatile("s_waitcnt lgkmcnt(0)" ::: "memory");
  __builtin_amdgcn_s_barrier();
  __builtin_amdgcn_sched_barrier(0);
}

// ---- prep 1: fold weights to bf16, transposed; also Wsum = W1a + W1c ----
__global__ void prep_weights(const float* __restrict__ W1, const float* __restrict__ W2,
                             const float* __restrict__ Wd, const float* __restrict__ bd,
                             u16* __restrict__ WbcT, u16* __restrict__ WdT,
                             u16* __restrict__ W2T, float* __restrict__ WdS,
                             float* __restrict__ Wsum){
  int n = blockIdx.x;      // h (0..255)
  int k = threadIdx.x;     // 0..255
  if (k < DD){
    WbcT[n * DD + k] = f2bf_rne(W1[(128 + k) * NH1 + n] - W1[(256 + k) * NH1 + n]);
    WdT [n * DD + k] = f2bf_rne(W1[(384 + k) * NH1 + n]);
    Wsum[k * NH1 + n] = W1[k * NH1 + n] + W1[(256 + k) * NH1 + n];
  }
  if (n < NH2) W2T[n * 256 + k] = f2bf_rne(W2[k * NH2 + n]);
  if (n == 0 && k < NH2) WdS[k] = Wd[k];
  if (n == 0 && k == NH2) WdS[NH2] = bd[0];
}

// ---- prep 2: per-batch layer1 bias = b1 + q @ Wsum ----
__global__ void prep_bias(const float* __restrict__ q, const float* __restrict__ Wsum,
                          const float* __restrict__ b1, float* __restrict__ bias1){
  __shared__ float qsh[DD];
  int b = blockIdx.x, j = threadIdx.x;
  if (j < DD) qsh[j] = q[b * DD + j];
  __syncthreads();
  float acc = b1[j];
  #pragma unroll 8
  for (int d = 0; d < DD; ++d)
    acc += qsh[d] * Wsum[d * NH1 + j];
  bias1[b * NH1 + j] = acc;
}

// ---- main: one block per batch, 8 waves, 8 s-tiles of 32 rows ----
__global__ __launch_bounds__(512, 4)
void seqatt_main(const float* __restrict__ queries, const float* __restrict__ keys,
                 const int* __restrict__ keys_length,
                 const u16* __restrict__ WbcT, const u16* __restrict__ WdT,
                 const u16* __restrict__ W2Tg,
                 const float* __restrict__ WdS, const float* __restrict__ bias1g,
                 const float* __restrict__ b2g, float* __restrict__ out)
{
  __shared__ alignas(16) char smem[L_SIZE];
  float* scores = (float*)(smem + L_SCORES);
  float* bias1s = (float*)(smem + L_BIAS);
  float* b2s    = (float*)(smem + L_B2);
  float* wds    = (float*)(smem + L_WD);
  float* wpart  = (float*)(smem + L_WPART);
  float* red4   = (float*)(smem + L_RED4);

  const int b = blockIdx.x;
  const int tid = threadIdx.x;
  const int lane = tid & 63;
  const int wave = tid >> 6;          // 0..7
  const int l15 = lane & 15;
  const int g   = lane >> 4;          // 0..3
  const int r = tid >> 4, seg = tid & 15;        // staging: 16 threads/row
  const int dcol = tid & 127, so = (tid >> 7) << 3;  // ACCUM: 1 d x 8 s per thread

  if (tid < 256) bias1s[tid] = bias1g[b * NH1 + tid];
  if (tid < 64) b2s[tid] = b2g[tid];
  if (tid < 65) wds[tid] = WdS[tid];
  const int klen = keys_length[b];
  const float* kbb = keys + (long)b * SLEN * DD;
  float out_acc = 0.f;

  // staging registers (8 floats/thread/tile)
  float4 k0, k1;
#define ISSUE(t) do { const float* p_ = kbb + (((t) << 5) + r) * DD + (seg << 3); \
    k0 = *(const float4*)p_; k1 = *(const float4*)(p_ + 4); } while (0)
#define STORE(t) do { int bb_ = ((t) % 3) * 8192 + (r << 8) + (seg << 4); \
    uint4 w_; \
    w_.x = pack_trunc(k0.x, k0.y); w_.y = pack_trunc(k0.z, k0.w); \
    w_.z = pack_trunc(k1.x, k1.y); w_.w = pack_trunc(k1.z, k1.w); \
    *(uint4*)(smem + swzk(bb_)) = w_; } while (0)
  // ACCUM(t): out_acc += sum_{i} e[t*32+so+i] * kbuf[t%3][so+i][dcol]
  // swzk of (row*256 + dcol*2): row = so+i, so%8==0 -> xor key = i<<4.
#define ACCUM(t) do { const int kb3_ = ((t) % 3) * 8192; \
    _Pragma("unroll") \
    for (int i_ = 0; i_ < 8; ++i_){ \
      float w_ = scores[((t) << 5) + so + i_]; \
      u16 kv_ = *(const u16*)(smem + kb3_ + ((so + i_) << 8) + ((dcol << 1) ^ (i_ << 4))); \
      out_acc = fmaf(w_, b2fl((short)kv_), out_acc); \
    } } while (0)

  ISSUE(0);

  // Weff fragments (GEMM1 A-operand), h-slice = wave*32..+32: 32 VGPRs
  bf16x8 bfrag[2][4];
  {
    const float* qb = queries + b * DD;
    #pragma unroll
    for (int nt = 0; nt < 2; ++nt){
      int n = (wave << 5) + (nt << 4) + l15;
      #pragma unroll
      for (int kk = 0; kk < 4; ++kk){
        int k0i = (g << 3) + (kk << 5);
        bf16x8 bc = *(const bf16x8*)(WbcT + n * DD + k0i);
        bf16x8 wd = *(const bf16x8*)(WdT  + n * DD + k0i);
        float4 q0 = *(const float4*)(qb + k0i);
        float4 q1 = *(const float4*)(qb + k0i + 4);
        float qa[8] = {q0.x, q0.y, q0.z, q0.w, q1.x, q1.y, q1.z, q1.w};
        union { u16 s[8]; bf16x8 v; } o;
        #pragma unroll
        for (int j = 0; j < 8; ++j)
          o.s[j] = f2bf_rne(fmaf(qa[j], b2fl(wd[j]), b2fl(bc[j])));
        bfrag[nt][kk] = o.v;
      }
    }
  }
  // GEMM2 split: wave = (s-half sh)*4 + o-slice; full K=256: w2frag 32 VGPRs
  const int sh = wave >> 2;           // 0..1: s-rows sh*16..+16
  const int ob = (wave & 3) << 4;     // o-slice base
  bf16x8 w2frag[8];
  #pragma unroll
  for (int kk = 0; kk < 8; ++kk)
    w2frag[kk] = *(const bf16x8*)(W2Tg + (ob + l15) * 256 + (kk << 5) + (g << 3));

  STORE(0);
  barrier_lds();   // kbuf[0], scalars visible

  const f32x4 fz = {0.f, 0.f, 0.f, 0.f};

  #pragma unroll
  for (int st = 0; st < 8; ++st){
    const int kb_base = (st % 3) * 8192;

    if (st < 7) ISSUE(st + 1);   // global->reg, flies under GEMM1+GEMM2

    // ---- GEMM1 (swapped): lane holds h1^T: s = mt*16+l15, h = wave*32+nt*16+g*4+i ----
    f32x4 acc[2][2];
    #pragma unroll
    for (int mt = 0; mt < 2; ++mt)
      #pragma unroll
      for (int nt = 0; nt < 2; ++nt) acc[mt][nt] = fz;
    #pragma unroll
    for (int kk = 0; kk < 4; ++kk){
      bf16x8 af[2];
      #pragma unroll
      for (int mt = 0; mt < 2; ++mt)
        af[mt] = *(const bf16x8*)(smem + swzk(kb_base + (((mt << 4) + l15) << 8) + (kk << 6) + (g << 4)));
      #pragma unroll
      for (int mt = 0; mt < 2; ++mt)
        #pragma unroll
        for (int nt = 0; nt < 2; ++nt)
          acc[mt][nt] = __builtin_amdgcn_mfma_f32_16x16x32_bf16(bfrag[nt][kk], af[mt], acc[mt][nt], 0, 0, 0);
    }

    // ---- bias + sigmoid -> h1 LDS bf16, vector 8B writes (own h-columns) ----
    #pragma unroll
    for (int nt = 0; nt < 2; ++nt){
      float4 bia = *(const float4*)(bias1s + (wave << 5) + (nt << 4) + (g << 2));
      #pragma unroll
      for (int mt = 0; mt < 2; ++mt){
        float v0 = fsigmoid(acc[mt][nt][0] + bia.x);
        float v1 = fsigmoid(acc[mt][nt][1] + bia.y);
        float v2 = fsigmoid(acc[mt][nt][2] + bia.z);
        float v3 = fsigmoid(acc[mt][nt][3] + bia.w);
        uint2 p; p.x = pack_trunc(v0, v1); p.y = pack_trunc(v2, v3);
        int s = (mt << 4) + l15;
        int hb = (wave << 5) + (nt << 4) + (g << 2);
        *(uint2*)(smem + swz(L_H1 + (s << 9) + (hb << 1))) = p;
      }
    }
    barrier_lds();   // (E) h1 visible; also orders ACCUM(st-1) after finalize(st-1)

    // ---- fused out-accumulation for previous tile (kbuf[st-1] still intact) ----
    if (st > 0) ACCUM(st - 1);

    // ---- GEMM2 (swapped): rows s = sh*16+l15, o-slice ob..+16, K=256 (2x4 chain) ----
    f32x4 acc2a = fz, acc2b = fz;
    #pragma unroll
    for (int kk = 0; kk < 4; ++kk){
      bf16x8 a2 = *(const bf16x8*)(smem + swz(L_H1 + (((sh << 4) + l15) << 9) + (kk << 6) + (g << 4)));
      acc2a = __builtin_amdgcn_mfma_f32_16x16x32_bf16(w2frag[kk], a2, acc2a, 0, 0, 0);
    }
    #pragma unroll
    for (int kk = 4; kk < 8; ++kk){
      bf16x8 a2 = *(const bf16x8*)(smem + swz(L_H1 + (((sh << 4) + l15) << 9) + (kk << 6) + (g << 4)));
      acc2b = __builtin_amdgcn_mfma_f32_16x16x32_bf16(w2frag[kk], a2, acc2b, 0, 0, 0);
    }

    // ---- sigmoid + Wd dot + reduce over g -> wpart[o-slice][s] ----
    {
      float pp = 0.f;
      #pragma unroll
      for (int i = 0; i < 4; ++i){
        int o = ob + (g << 2) + i;
        pp += fsigmoid((acc2a[i] + acc2b[i]) + b2s[o]) * wds[o];
      }
      pp += __shfl_xor(pp, 16); pp += __shfl_xor(pp, 32);
      if (lane < 16)
        wpart[((wave & 3) << 5) + (sh << 4) + l15] = pp;
    }

    if (st < 7) STORE(st + 1);   // write-late into kbuf[(st+1)%3]

    barrier_lds();   // (G) wpart + next kbuf visible; h1/kbuf reads done

    // ---- finalize: e = exp(score) (masked 0) -> scores[st*32..+32] ----
    if (tid < 32){
      float v = wpart[tid] + wpart[32 + tid] + wpart[64 + tid] + wpart[96 + tid];
      int s = (st << 5) + tid;
      float sc = (v + wds[64]) * 0.08838834764831845f;   // 1/sqrt(128)
      scores[s] = (s < klen) ? __expf(sc) : 0.f;         // bounded: |sc| < ~1
    }
  }

  barrier_lds();   // finalize(7) visible
  ACCUM(7);        // kbuf[1] still intact (no STORE after tile 7)

  // ---- total = sum of e over S ----
  float tot;
  {
    float v = (tid < 256) ? scores[tid] : 0.f;
    #pragma unroll
    for (int off = 32; off >= 1; off >>= 1) v += __shfl_xor(v, off);
    if (lane == 0) red4[wave] = v;
    __syncthreads();
    tot = ((red4[0] + red4[1]) + (red4[2] + red4[3])) +
          ((red4[4] + red4[5]) + (red4[6] + red4[7]));
  }

  // ---- reduce out partials: 4 s-octant groups per d ----
  {
    float* red = (float*)smem;   // kbuf area (ACCUM(7) reads done: __syncthreads above)
    red[tid] = out_acc;
    __syncthreads();
    if (tid < 128)
      out[b * DD + tid] = ((red[tid] + red[128 + tid]) + (red[256 + tid] + red[384 + tid]))
                          * __builtin_amdgcn_rcpf(tot);
  }
#undef ISSUE
#undef STORE
#undef ACCUM
}

extern "C" void kernel_launch(void* const* d_in, const int* in_sizes, int n_in,
                              void* d_out, int out_size, void* d_ws, size_t ws_size,
                              hipStream_t stream) {
  const float* queries     = (const float*)d_in[0];
  const float* keys        = (const float*)d_in[1];
  const int*   keys_length = (const int*)d_in[2];
  const float* W1 = (const float*)d_in[3];
  const float* b1 = (const float*)d_in[4];
  const float* W2 = (const float*)d_in[5];
  const float* b2 = (const float*)d_in[6];
  const float* Wd = (const float*)d_in[7];
  const float* bd = (const float*)d_in[8];
  float* out = (float*)d_out;
  char* ws = (char*)d_ws;

  u16*   WbcT  = (u16*)(ws + WS_WBCT);
  u16*   WdT   = (u16*)(ws + WS_WDT);
  u16*   W2T   = (u16*)(ws + WS_W2T);
  float* WdS   = (float*)(ws + WS_WDS);
  float* Wsum  = (float*)(ws + WS_WSUM);
  float* bias1 = (float*)(ws + WS_BIAS1);

  prep_weights<<<dim3(256), dim3(256), 0, stream>>>(W1, W2, Wd, bd, WbcT, WdT, W2T, WdS, Wsum);
  prep_bias<<<dim3(NBATCH), dim3(256), 0, stream>>>(queries, Wsum, b1, bias1);
  seqatt_main<<<dim3(NBATCH), dim3(512), 0, stream>>>(queries, keys, keys_length,
                                                      WbcT, WdT, W2T, WdS, bias1, b2, out);
}

// Round 14
// 134.446 us; speedup vs baseline: 1.5663x; 1.5663x over previous
//
#include <hip/hip_runtime.h>

// B=1024, S=256, D=128, H1=256, H2=64.
// h1_pre[s,h] = bias1[b,h] + sum_d keys[s,d] * Weff_b[d,h]   (K=128 GEMM)
//   Weff_b[d,h] = (W1b - W1c)[d,h] + q_b[d] * W1d[d,h]
//   bias1[b,h]  = b1[h] + q_b @ (W1a + W1c)
// R14: split-grid two-pass. Pass1 = R12 tile engine, 2048 blocks (2/batch,
//   4 tiles each): halves the per-block serial chain that three ~90us
//   structures shared; writes e=exp(score) (no-max softmax, bounded |score|<1)
//   to ws. Pass2 = 1024-block finish: tot=sum(e), out = (sum_s e*keys)/tot,
//   keys L2/L3-resident. Register pressure <= R12 -> (512,4) safe.

typedef unsigned short u16;
typedef unsigned int u32;
typedef short bf16x8 __attribute__((ext_vector_type(8)));
typedef float f32x4 __attribute__((ext_vector_type(4)));

#define NBATCH 1024
#define SLEN 256
#define DD 128
#define NH1 256
#define NH2 64

// ws layout (bytes)
#define WS_WBCT  0         // [256h][128k] bf16  (W1b - W1c)^T
#define WS_WDT   65536     // [256h][128k] bf16  W1d^T
#define WS_W2T   131072    // [64o][256h]  bf16  W2^T
#define WS_WDS   163840    // 65 f32 (Wd[64], bd)
#define WS_WSUM  165888    // [128d][256h] f32   W1a + W1c
#define WS_BIAS1 296960    // [1024][256] f32
#define WS_ESC   1345536   // [1024][256] f32  e-values

// LDS map (pass-1 kernel)
#define L_KBUF   0         // [2][32][128] bf16, swzk (2 x 8KB)
#define L_H1     16384     // h1 bf16 [32 s][256 h] = [32][512B], swz
#define L_BIAS   32768     // f32[256]
#define L_B2     33792     // f32[64]
#define L_WD     34048     // f32[66] (pad)
#define L_WPART  34320     // f32[4][32]
#define L_SIZE   34832

__device__ __forceinline__ u16 f2bf_rne(float f){
  union { float f; unsigned u; } v; v.f = f;
  unsigned r = v.u + 0x7fffu + ((v.u >> 16) & 1u);
  return (u16)(r >> 16);
}
__device__ __forceinline__ u32 pack_trunc(float a, float b){
  return (__float_as_uint(a) >> 16) | (__float_as_uint(b) & 0xffff0000u);
}
__device__ __forceinline__ float b2fl(short s){
  return __uint_as_float(((u32)(u16)s) << 16);
}
__device__ __forceinline__ int swz(int byte){    // h1: 512B rows
  return byte ^ (((byte >> 9) & 7) << 4);
}
__device__ __forceinline__ int swzk(int byte){   // kbuf: 256B rows
  return byte ^ (((byte >> 8) & 7) << 4);
}
__device__ __forceinline__ float fsigmoid(float x){
  return __builtin_amdgcn_rcpf(1.f + __expf(-x));
}
__device__ __forceinline__ void barrier_lds(){
  asm volatile("s_waitcnt lgkmcnt(0)" ::: "memory");
  __builtin_amdgcn_s_barrier();
  __builtin_amdgcn_sched_barrier(0);
}

// ---- prep 1: fold weights to bf16, transposed; also Wsum = W1a + W1c ----
__global__ void prep_weights(const float* __restrict__ W1, const float* __restrict__ W2,
                             const float* __restrict__ Wd, const float* __restrict__ bd,
                             u16* __restrict__ WbcT, u16* __restrict__ WdT,
                             u16* __restrict__ W2T, float* __restrict__ WdS,
                             float* __restrict__ Wsum){
  int n = blockIdx.x;      // h (0..255)
  int k = threadIdx.x;     // 0..255
  if (k < DD){
    WbcT[n * DD + k] = f2bf_rne(W1[(128 + k) * NH1 + n] - W1[(256 + k) * NH1 + n]);
    WdT [n * DD + k] = f2bf_rne(W1[(384 + k) * NH1 + n]);
    Wsum[k * NH1 + n] = W1[k * NH1 + n] + W1[(256 + k) * NH1 + n];
  }
  if (n < NH2) W2T[n * 256 + k] = f2bf_rne(W2[k * NH2 + n]);
  if (n == 0 && k < NH2) WdS[k] = Wd[k];
  if (n == 0 && k == NH2) WdS[NH2] = bd[0];
}

// ---- prep 2: per-batch layer1 bias = b1 + q @ Wsum ----
__global__ void prep_bias(const float* __restrict__ q, const float* __restrict__ Wsum,
                          const float* __restrict__ b1, float* __restrict__ bias1){
  __shared__ float qsh[DD];
  int b = blockIdx.x, j = threadIdx.x;
  if (j < DD) qsh[j] = q[b * DD + j];
  __syncthreads();
  float acc = b1[j];
  #pragma unroll 8
  for (int d = 0; d < DD; ++d)
    acc += qsh[d] * Wsum[d * NH1 + j];
  bias1[b * NH1 + j] = acc;
}

// ---- pass 1: 2048 blocks (2 per batch), 8 waves, 4 s-tiles of 32 rows ----
__global__ __launch_bounds__(512, 4)
void seqatt_scores(const float* __restrict__ queries, const float* __restrict__ keys,
                   const int* __restrict__ keys_length,
                   const u16* __restrict__ WbcT, const u16* __restrict__ WdT,
                   const u16* __restrict__ W2Tg,
                   const float* __restrict__ WdS, const float* __restrict__ bias1g,
                   const float* __restrict__ b2g, float* __restrict__ escore)
{
  __shared__ alignas(16) char smem[L_SIZE];
  float* bias1s = (float*)(smem + L_BIAS);
  float* b2s    = (float*)(smem + L_B2);
  float* wds    = (float*)(smem + L_WD);
  float* wpart  = (float*)(smem + L_WPART);

  const int b    = blockIdx.x >> 1;
  const int half = blockIdx.x & 1;     // s-half: tiles half*4 .. half*4+3
  const int tid = threadIdx.x;
  const int lane = tid & 63;
  const int wave = tid >> 6;          // 0..7
  const int l15 = lane & 15;
  const int g   = lane >> 4;          // 0..3
  const int r = tid >> 4, seg = tid & 15;  // staging: 16 threads/row, 8 floats each

  if (tid < 256) bias1s[tid] = bias1g[b * NH1 + tid];
  if (tid < 64) b2s[tid] = b2g[tid];
  if (tid < 65) wds[tid] = WdS[tid];
  const int klen = keys_length[b];
  const float* kbb = keys + (long)b * SLEN * DD;

  // staging registers (8 floats/thread/tile); t = GLOBAL tile index
  float4 k0, k1;
#define ISSUE(t) do { const float* p_ = kbb + (((t) << 5) + r) * DD + (seg << 3); \
    k0 = *(const float4*)p_; k1 = *(const float4*)(p_ + 4); } while (0)
#define STORE(t) do { int bb_ = (((t) & 1) << 13) + (r << 8) + (seg << 4); \
    uint4 w_; \
    w_.x = pack_trunc(k0.x, k0.y); w_.y = pack_trunc(k0.z, k0.w); \
    w_.z = pack_trunc(k1.x, k1.y); w_.w = pack_trunc(k1.z, k1.w); \
    *(uint4*)(smem + swzk(bb_)) = w_; } while (0)

  const int t0 = half << 2;
  ISSUE(t0);

  // Weff fragments (GEMM1 A-operand), h-slice = wave*32..+32: 32 VGPRs
  bf16x8 bfrag[2][4];
  {
    const float* qb = queries + b * DD;
    #pragma unroll
    for (int nt = 0; nt < 2; ++nt){
      int n = (wave << 5) + (nt << 4) + l15;
      #pragma unroll
      for (int kk = 0; kk < 4; ++kk){
        int k0i = (g << 3) + (kk << 5);
        bf16x8 bc = *(const bf16x8*)(WbcT + n * DD + k0i);
        bf16x8 wd = *(const bf16x8*)(WdT  + n * DD + k0i);
        float4 q0 = *(const float4*)(qb + k0i);
        float4 q1 = *(const float4*)(qb + k0i + 4);
        float qa[8] = {q0.x, q0.y, q0.z, q0.w, q1.x, q1.y, q1.z, q1.w};
        union { u16 s[8]; bf16x8 v; } o;
        #pragma unroll
        for (int j = 0; j < 8; ++j)
          o.s[j] = f2bf_rne(fmaf(qa[j], b2fl(wd[j]), b2fl(bc[j])));
        bfrag[nt][kk] = o.v;
      }
    }
  }
  // GEMM2 split: wave = (s-half sh)*4 + o-slice; full K=256: w2frag 32 VGPRs
  const int sh = wave >> 2;           // 0..1: s-rows sh*16..+16
  const int ob = (wave & 3) << 4;     // o-slice base
  bf16x8 w2frag[8];
  #pragma unroll
  for (int kk = 0; kk < 8; ++kk)
    w2frag[kk] = *(const bf16x8*)(W2Tg + (ob + l15) * 256 + (kk << 5) + (g << 3));

  STORE(t0);
  barrier_lds();   // kbuf[t0&1], scalars visible

  const f32x4 fz = {0.f, 0.f, 0.f, 0.f};

  #pragma unroll
  for (int st = 0; st < 4; ++st){
    const int t = t0 + st;
    const int kb_base = (t & 1) << 13;

    if (st < 3) ISSUE(t + 1);   // global->reg, flies under GEMM1+GEMM2

    // ---- GEMM1 (swapped): lane holds h1^T: s = mt*16+l15, h = wave*32+nt*16+g*4+i ----
    f32x4 acc[2][2];
    #pragma unroll
    for (int mt = 0; mt < 2; ++mt)
      #pragma unroll
      for (int nt = 0; nt < 2; ++nt) acc[mt][nt] = fz;
    #pragma unroll
    for (int kk = 0; kk < 4; ++kk){
      bf16x8 af[2];
      #pragma unroll
      for (int mt = 0; mt < 2; ++mt)
        af[mt] = *(const bf16x8*)(smem + swzk(kb_base + (((mt << 4) + l15) << 8) + (kk << 6) + (g << 4)));
      #pragma unroll
      for (int mt = 0; mt < 2; ++mt)
        #pragma unroll
        for (int nt = 0; nt < 2; ++nt)
          acc[mt][nt] = __builtin_amdgcn_mfma_f32_16x16x32_bf16(bfrag[nt][kk], af[mt], acc[mt][nt], 0, 0, 0);
    }

    // ---- bias + sigmoid -> h1 LDS bf16, vector 8B writes (own h-columns) ----
    #pragma unroll
    for (int nt = 0; nt < 2; ++nt){
      float4 bia = *(const float4*)(bias1s + (wave << 5) + (nt << 4) + (g << 2));
      #pragma unroll
      for (int mt = 0; mt < 2; ++mt){
        float v0 = fsigmoid(acc[mt][nt][0] + bia.x);
        float v1 = fsigmoid(acc[mt][nt][1] + bia.y);
        float v2 = fsigmoid(acc[mt][nt][2] + bia.z);
        float v3 = fsigmoid(acc[mt][nt][3] + bia.w);
        uint2 p; p.x = pack_trunc(v0, v1); p.y = pack_trunc(v2, v3);
        int s = (mt << 4) + l15;
        int hb = (wave << 5) + (nt << 4) + (g << 2);
        *(uint2*)(smem + swz(L_H1 + (s << 9) + (hb << 1))) = p;
      }
    }
    barrier_lds();   // (E) h1 visible to all waves

    // ---- GEMM2 (swapped): rows s = sh*16+l15, o-slice ob..+16, K=256 (2x4) ----
    f32x4 acc2a = fz, acc2b = fz;
    #pragma unroll
    for (int kk = 0; kk < 4; ++kk){
      bf16x8 a2 = *(const bf16x8*)(smem + swz(L_H1 + (((sh << 4) + l15) << 9) + (kk << 6) + (g << 4)));
      acc2a = __builtin_amdgcn_mfma_f32_16x16x32_bf16(w2frag[kk], a2, acc2a, 0, 0, 0);
    }
    #pragma unroll
    for (int kk = 4; kk < 8; ++kk){
      bf16x8 a2 = *(const bf16x8*)(smem + swz(L_H1 + (((sh << 4) + l15) << 9) + (kk << 6) + (g << 4)));
      acc2b = __builtin_amdgcn_mfma_f32_16x16x32_bf16(w2frag[kk], a2, acc2b, 0, 0, 0);
    }

    // ---- sigmoid + Wd dot + reduce over g -> wpart[o-slice][s] ----
    {
      float pp = 0.f;
      #pragma unroll
      for (int i = 0; i < 4; ++i){
        int o = ob + (g << 2) + i;
        pp += fsigmoid((acc2a[i] + acc2b[i]) + b2s[o]) * wds[o];
      }
      pp += __shfl_xor(pp, 16); pp += __shfl_xor(pp, 32);
      if (lane < 16)
        wpart[((wave & 3) << 5) + (sh << 4) + l15] = pp;
    }

    if (st < 3) STORE(t + 1);   // write-late into other kbuf

    barrier_lds();   // (G) wpart + next kbuf visible; h1/kbuf reads done

    // ---- finalize: e = exp(score) (masked 0) -> escore[b][t*32..+32] ----
    if (tid < 32){
      float v = wpart[tid] + wpart[32 + tid] + wpart[64 + tid] + wpart[96 + tid];
      int s = (t << 5) + tid;
      float sc = (v + wds[64]) * 0.08838834764831845f;   // 1/sqrt(128)
      escore[b * SLEN + s] = (s < klen) ? __expf(sc) : 0.f;   // bounded: |sc| < ~1
    }
    // next (E) barrier orders: this tile's wpart reads before next writes
  }
#undef ISSUE
#undef STORE
}

// ---- pass 2: normalize + weighted key sum (keys L2/L3-resident) ----
__global__ __launch_bounds__(256)
void seqatt_finish(const float* __restrict__ escore, const float* __restrict__ keys,
                   float* __restrict__ out)
{
  __shared__ float esm[256];
  __shared__ float red[256];
  __shared__ float r4[4];
  const int b = blockIdx.x, tid = threadIdx.x;
  const int lane = tid & 63, wave = tid >> 6;

  float e = escore[b * SLEN + tid];
  esm[tid] = e;
  float v = e;
  #pragma unroll
  for (int off = 32; off >= 1; off >>= 1) v += __shfl_xor(v, off);
  if (lane == 0) r4[wave] = v;
  __syncthreads();
  const float tot = (r4[0] + r4[1]) + (r4[2] + r4[3]);

  const int d = tid & 127, hf = tid >> 7;
  const float* kb = keys + ((long)b * SLEN + hf * 128) * DD + d;
  const float* ep = esm + hf * 128;
  float acc = 0.f;
  #pragma unroll 8
  for (int s2 = 0; s2 < 128; ++s2) acc = fmaf(ep[s2], kb[s2 * DD], acc);
  red[tid] = acc;
  __syncthreads();
  if (tid < 128)
    out[b * DD + tid] = (red[tid] + red[128 + tid]) * __builtin_amdgcn_rcpf(tot);
}

extern "C" void kernel_launch(void* const* d_in, const int* in_sizes, int n_in,
                              void* d_out, int out_size, void* d_ws, size_t ws_size,
                              hipStream_t stream) {
  const float* queries     = (const float*)d_in[0];
  const float* keys        = (const float*)d_in[1];
  const int*   keys_length = (const int*)d_in[2];
  const float* W1 = (const float*)d_in[3];
  const float* b1 = (const float*)d_in[4];
  const float* W2 = (const float*)d_in[5];
  const float* b2 = (const float*)d_in[6];
  const float* Wd = (const float*)d_in[7];
  const float* bd = (const float*)d_in[8];
  float* out = (float*)d_out;
  char* ws = (char*)d_ws;

  u16*   WbcT   = (u16*)(ws + WS_WBCT);
  u16*   WdT    = (u16*)(ws + WS_WDT);
  u16*   W2T    = (u16*)(ws + WS_W2T);
  float* WdS    = (float*)(ws + WS_WDS);
  float* Wsum   = (float*)(ws + WS_WSUM);
  float* bias1  = (float*)(ws + WS_BIAS1);
  float* escore = (float*)(ws + WS_ESC);

  prep_weights<<<dim3(256), dim3(256), 0, stream>>>(W1, W2, Wd, bd, WbcT, WdT, W2T, WdS, Wsum);
  prep_bias<<<dim3(NBATCH), dim3(256), 0, stream>>>(queries, Wsum, b1, bias1);
  seqatt_scores<<<dim3(NBATCH * 2), dim3(512), 0, stream>>>(queries, keys, keys_length,
                                                            WbcT, WdT, W2T, WdS, bias1, b2, escore);
  seqatt_finish<<<dim3(NBATCH), dim3(256), 0, stream>>>(escore, keys, out);
}

// Round 15
// 101.785 us; speedup vs baseline: 2.0689x; 1.3209x over previous
//
#include <hip/hip_runtime.h>

// B=1024, S=256, D=128, H1=256, H2=64.
// h1_pre[s,h] = bias1[b,h] + sum_d keys[s,d] * Weff_b[d,h]   (K=128 GEMM)
//   Weff_b[d,h] = (W1b - W1c)[d,h] + q_b[d] * W1d[d,h]
//   bias1[b,h]  = b1[h] + q_b @ (W1a + W1c)
// R15 = R12 with the VALU/address phase attacked:
//   - NO XOR swizzle: padded rows (kbuf stride 272B, h1 stride 528B).
//     stride = 4 dwords mod 32 banks -> all patterns 2-way or optimal (free).
//   - per-lane LDS base addresses hoisted out of the loop; full 8-tile unroll
//     makes every ds offset a compile-time immediate.
//   - exp2-fold: Weff/Wsum/b1/W2T/b2 and score-scale pre-multiplied by log2(e)
//     at prep; sigmoid = rcp(1+exp2(-x)), softmax exp = exp2. Saves the mul in
//     every transcendental.

typedef unsigned short u16;
typedef unsigned int u32;
typedef short bf16x8 __attribute__((ext_vector_type(8)));
typedef float f32x4 __attribute__((ext_vector_type(4)));

#define NBATCH 1024
#define SLEN 256
#define DD 128
#define NH1 256
#define NH2 64
#define LOG2E 1.4426950408889634f

// ws layout (bytes)
#define WS_WBCT  0         // [256h][128k] bf16  (W1b - W1c)^T * log2e
#define WS_WDT   65536     // [256h][128k] bf16  W1d^T * log2e
#define WS_W2T   131072    // [64o][256h]  bf16  W2^T * log2e
#define WS_WDS   163840    // 65 f32 (Wd[64], bd)
#define WS_WSUM  165888    // [128d][256h] f32   (W1a + W1c) * log2e
#define WS_BIAS1 296960    // [1024][256] f32    (log2e-scaled)

// LDS map (main kernel) — padded rows, no swizzle
#define KROW     272       // kbuf row stride (32 rows)
#define KBUFSZ   8704      // 32*272
#define H1ROW    528       // h1 row stride
#define L_H1     17408     // 2*KBUFSZ
#define L_BIAS   34304     // L_H1 + 32*528 = 34304 ; f32[256]
#define L_B2     35328     // f32[64]
#define L_WD     35584     // f32[66] (pad)
#define L_WPART  35856     // f32[4][32]
#define L_SCORES 36368     // f32[256]
#define L_RED4   37392     // f32[16]
#define L_SIZE   37456

__device__ __forceinline__ u16 f2bf_rne(float f){
  union { float f; unsigned u; } v; v.f = f;
  unsigned r = v.u + 0x7fffu + ((v.u >> 16) & 1u);
  return (u16)(r >> 16);
}
__device__ __forceinline__ u32 pack_trunc(float a, float b){
  return (__float_as_uint(a) >> 16) | (__float_as_uint(b) & 0xffff0000u);
}
__device__ __forceinline__ float b2fl(short s){
  return __uint_as_float(((u32)(u16)s) << 16);
}
__device__ __forceinline__ float fsig2(float x){   // input pre-scaled by log2e
  return __builtin_amdgcn_rcpf(1.f + exp2f(-x));
}
__device__ __forceinline__ void barrier_lds(){
  asm volatile("s_waitcnt lgkmcnt(0)" ::: "memory");
  __builtin_amdgcn_s_barrier();
  __builtin_amdgcn_sched_barrier(0);
}

// ---- prep 1: fold weights to bf16 (log2e-scaled), transposed ----
__global__ void prep_weights(const float* __restrict__ W1, const float* __restrict__ W2,
                             const float* __restrict__ Wd, const float* __restrict__ bd,
                             u16* __restrict__ WbcT, u16* __restrict__ WdT,
                             u16* __restrict__ W2T, float* __restrict__ WdS,
                             float* __restrict__ Wsum){
  int n = blockIdx.x;      // h (0..255)
  int k = threadIdx.x;     // 0..255
  if (k < DD){
    WbcT[n * DD + k] = f2bf_rne((W1[(128 + k) * NH1 + n] - W1[(256 + k) * NH1 + n]) * LOG2E);
    WdT [n * DD + k] = f2bf_rne(W1[(384 + k) * NH1 + n] * LOG2E);
    Wsum[k * NH1 + n] = (W1[k * NH1 + n] + W1[(256 + k) * NH1 + n]) * LOG2E;
  }
  if (n < NH2) W2T[n * 256 + k] = f2bf_rne(W2[k * NH2 + n] * LOG2E);
  if (n == 0 && k < NH2) WdS[k] = Wd[k];
  if (n == 0 && k == NH2) WdS[NH2] = bd[0];
}

// ---- prep 2: per-batch layer1 bias = (b1 + q @ Wsum/log2e)*log2e ----
__global__ void prep_bias(const float* __restrict__ q, const float* __restrict__ Wsum,
                          const float* __restrict__ b1, float* __restrict__ bias1){
  __shared__ float qsh[DD];
  int b = blockIdx.x, j = threadIdx.x;
  if (j < DD) qsh[j] = q[b * DD + j];
  __syncthreads();
  float acc = b1[j] * LOG2E;
  #pragma unroll 8
  for (int d = 0; d < DD; ++d)
    acc += qsh[d] * Wsum[d * NH1 + j];     // Wsum already log2e-scaled
  bias1[b * NH1 + j] = acc;
}

// ---- main: one block per batch, 8 waves, 8 s-tiles of 32 rows ----
__global__ __launch_bounds__(512, 4)
void seqatt_main(const float* __restrict__ queries, const float* __restrict__ keys,
                 const int* __restrict__ keys_length,
                 const u16* __restrict__ WbcT, const u16* __restrict__ WdT,
                 const u16* __restrict__ W2Tg,
                 const float* __restrict__ WdS, const float* __restrict__ bias1g,
                 const float* __restrict__ b2g, float* __restrict__ out)
{
  __shared__ alignas(16) char smem[L_SIZE];
  float* bias1s = (float*)(smem + L_BIAS);
  float* b2s    = (float*)(smem + L_B2);
  float* wds    = (float*)(smem + L_WD);
  float* wpart  = (float*)(smem + L_WPART);
  float* scores = (float*)(smem + L_SCORES);
  float* red4   = (float*)(smem + L_RED4);

  const int b = blockIdx.x;
  const int tid = threadIdx.x;
  const int lane = tid & 63;
  const int wave = tid >> 6;          // 0..7
  const int l15 = lane & 15;
  const int g   = lane >> 4;          // 0..3
  const int r = tid >> 4, seg = tid & 15;  // staging: 16 threads/row, 8 floats each

  if (tid < 256) bias1s[tid] = bias1g[b * NH1 + tid];
  if (tid < 64) b2s[tid] = b2g[tid] * LOG2E;
  if (tid < 65) wds[tid] = WdS[tid];
  const int klen = keys_length[b];
  const float* kbb = keys + (long)b * SLEN * DD;

  // hoisted per-lane LDS bases (linear layout, no swizzle)
  const int a1base = l15 * KROW + (g << 4);                    // GEMM1 read: +mt*4352 +kk*64 +buf
  const int hwbase = L_H1 + l15 * H1ROW + (((wave << 5) + (g << 2)) << 1);  // h1 write: +mt*8448 +nt*32
  const int stbase = r * KROW + (seg << 4);                    // staging write: +buf

  // staging registers (8 floats/thread/tile)
  float4 k0, k1;
#define ISSUE(t) do { const float* p_ = kbb + (((t) << 5) + r) * DD + (seg << 3); \
    k0 = *(const float4*)p_; k1 = *(const float4*)(p_ + 4); } while (0)
#define STORE(t) do { \
    uint4 w_; \
    w_.x = pack_trunc(k0.x, k0.y); w_.y = pack_trunc(k0.z, k0.w); \
    w_.z = pack_trunc(k1.x, k1.y); w_.w = pack_trunc(k1.z, k1.w); \
    *(uint4*)(smem + (((t) & 1) * KBUFSZ + stbase)) = w_; } while (0)

  ISSUE(0);

  // Weff fragments (GEMM1 A-operand), h-slice = wave*32..+32: 32 VGPRs
  bf16x8 bfrag[2][4];
  {
    const float* qb = queries + b * DD;
    #pragma unroll
    for (int nt = 0; nt < 2; ++nt){
      int n = (wave << 5) + (nt << 4) + l15;
      #pragma unroll
      for (int kk = 0; kk < 4; ++kk){
        int k0i = (g << 3) + (kk << 5);
        bf16x8 bc = *(const bf16x8*)(WbcT + n * DD + k0i);
        bf16x8 wd = *(const bf16x8*)(WdT  + n * DD + k0i);
        float4 q0 = *(const float4*)(qb + k0i);
        float4 q1 = *(const float4*)(qb + k0i + 4);
        float qa[8] = {q0.x, q0.y, q0.z, q0.w, q1.x, q1.y, q1.z, q1.w};
        union { u16 s[8]; bf16x8 v; } o;
        #pragma unroll
        for (int j = 0; j < 8; ++j)
          o.s[j] = f2bf_rne(fmaf(qa[j], b2fl(wd[j]), b2fl(bc[j])));
        bfrag[nt][kk] = o.v;
      }
    }
  }
  // GEMM2 split: wave = (s-half sh)*4 + o-slice; full K=256: w2frag 32 VGPRs
  const int sh = wave >> 2;           // 0..1: s-rows sh*16..+16
  const int ob = (wave & 3) << 4;     // o-slice base
  const int a2base = L_H1 + ((sh << 4) + l15) * H1ROW + (g << 4);  // GEMM2 read: +kk*64
  bf16x8 w2frag[8];
  #pragma unroll
  for (int kk = 0; kk < 8; ++kk)
    w2frag[kk] = *(const bf16x8*)(W2Tg + (ob + l15) * 256 + (kk << 5) + (g << 3));

  STORE(0);
  barrier_lds();   // kbuf[0], scalars visible

  const f32x4 fz = {0.f, 0.f, 0.f, 0.f};

  #pragma unroll
  for (int st = 0; st < 8; ++st){
    const int kb_base = (st & 1) * KBUFSZ;   // compile-time after unroll

    if (st < 7) ISSUE(st + 1);   // global->reg, flies under GEMM1+GEMM2

    // ---- GEMM1 (swapped): lane holds h1^T: s = mt*16+l15, h = wave*32+nt*16+g*4+i ----
    f32x4 acc[2][2];
    #pragma unroll
    for (int mt = 0; mt < 2; ++mt)
      #pragma unroll
      for (int nt = 0; nt < 2; ++nt) acc[mt][nt] = fz;
    #pragma unroll
    for (int kk = 0; kk < 4; ++kk){
      bf16x8 af[2];
      #pragma unroll
      for (int mt = 0; mt < 2; ++mt)
        af[mt] = *(const bf16x8*)(smem + (kb_base + a1base + mt * 4352 + (kk << 6)));
      #pragma unroll
      for (int mt = 0; mt < 2; ++mt)
        #pragma unroll
        for (int nt = 0; nt < 2; ++nt)
          acc[mt][nt] = __builtin_amdgcn_mfma_f32_16x16x32_bf16(bfrag[nt][kk], af[mt], acc[mt][nt], 0, 0, 0);
    }

    // ---- bias + sigmoid(exp2) -> h1 LDS bf16, vector 8B writes ----
    #pragma unroll
    for (int nt = 0; nt < 2; ++nt){
      float4 bia = *(const float4*)(bias1s + (wave << 5) + (nt << 4) + (g << 2));
      #pragma unroll
      for (int mt = 0; mt < 2; ++mt){
        float v0 = fsig2(acc[mt][nt][0] + bia.x);
        float v1 = fsig2(acc[mt][nt][1] + bia.y);
        float v2 = fsig2(acc[mt][nt][2] + bia.z);
        float v3 = fsig2(acc[mt][nt][3] + bia.w);
        uint2 p; p.x = pack_trunc(v0, v1); p.y = pack_trunc(v2, v3);
        *(uint2*)(smem + (hwbase + mt * 8448 + (nt << 5))) = p;
      }
    }
    barrier_lds();   // (E) h1 visible to all waves

    // ---- GEMM2 (swapped): rows s = sh*16+l15, o-slice ob..+16, K=256 (2x4) ----
    f32x4 acc2a = fz, acc2b = fz;
    #pragma unroll
    for (int kk = 0; kk < 4; ++kk){
      bf16x8 a2 = *(const bf16x8*)(smem + (a2base + (kk << 6)));
      acc2a = __builtin_amdgcn_mfma_f32_16x16x32_bf16(w2frag[kk], a2, acc2a, 0, 0, 0);
    }
    #pragma unroll
    for (int kk = 4; kk < 8; ++kk){
      bf16x8 a2 = *(const bf16x8*)(smem + (a2base + (kk << 6)));
      acc2b = __builtin_amdgcn_mfma_f32_16x16x32_bf16(w2frag[kk], a2, acc2b, 0, 0, 0);
    }

    // ---- sigmoid(exp2) + Wd dot + reduce over g -> wpart[o-slice][s] ----
    {
      float pp = 0.f;
      #pragma unroll
      for (int i = 0; i < 4; ++i){
        int o = ob + (g << 2) + i;
        pp += fsig2((acc2a[i] + acc2b[i]) + b2s[o]) * wds[o];
      }
      pp += __shfl_xor(pp, 16); pp += __shfl_xor(pp, 32);
      if (lane < 16)
        wpart[((wave & 3) << 5) + (sh << 4) + l15] = pp;
    }

    if (st < 7) STORE(st + 1);   // write-late into other kbuf

    barrier_lds();   // (G) wpart + next kbuf visible; h1/kbuf reads done

    // ---- finalize scores (log2 units) for this tile ----
    if (tid < 32){
      float v = wpart[tid] + wpart[32 + tid] + wpart[64 + tid] + wpart[96 + tid];
      int s = (st << 5) + tid;
      float sc = (v + wds[64]) * 0.12751744692290092f;   // log2e / sqrt(128)
      scores[s] = (s < klen) ? sc : -1e30f;
    }
    // next (E) barrier orders: this tile's wpart reads before next writes
  }

  barrier_lds();   // scores visible

  // ---- softmax over S=256 (scores in log2 units -> exp2) ----
  {
    float v = (tid < 256) ? scores[tid] : -1e30f;
    float m = v;
    #pragma unroll
    for (int off = 32; off >= 1; off >>= 1) m = fmaxf(m, __shfl_xor(m, off));
    if (lane == 0) red4[wave] = m;
    __syncthreads();
    float mx = red4[0];
    #pragma unroll
    for (int w = 1; w < 8; ++w) mx = fmaxf(mx, red4[w]);
    float e = (tid < 256) ? exp2f(v - mx) : 0.f;
    float ssum = e;
    #pragma unroll
    for (int off = 32; off >= 1; off >>= 1) ssum += __shfl_xor(ssum, off);
    if (lane == 0) red4[8 + wave] = ssum;
    __syncthreads();
    float tot = 0.f;
    #pragma unroll
    for (int w = 0; w < 8; ++w) tot += red4[8 + w];
    if (tid < 256) scores[tid] = e * __builtin_amdgcn_rcpf(tot);
    __syncthreads();
  }

  // ---- out[b][d] = sum_s w[s] * keys[b][s][d] (fp32; keys L2/L3-resident) ----
  {
    float* red = (float*)smem;   // kbuf area, free now
    int d = tid & 127, q4 = tid >> 7;   // 4 quarters of 64 s each
    const float* kb = keys + ((long)b * SLEN + q4 * 64) * DD + d;
    const float* sc = scores + q4 * 64;
    float acc = 0.f;
    #pragma unroll 4
    for (int s2 = 0; s2 < 64; ++s2) acc += sc[s2] * kb[s2 * DD];
    red[tid] = acc;
    __syncthreads();
    if (tid < 128)
      out[b * DD + tid] = (red[tid] + red[128 + tid]) + (red[256 + tid] + red[384 + tid]);
  }
#undef ISSUE
#undef STORE
}

extern "C" void kernel_launch(void* const* d_in, const int* in_sizes, int n_in,
                              void* d_out, int out_size, void* d_ws, size_t ws_size,
                              hipStream_t stream) {
  const float* queries     = (const float*)d_in[0];
  const float* keys        = (const float*)d_in[1];
  const int*   keys_length = (const int*)d_in[2];
  const float* W1 = (const float*)d_in[3];
  const float* b1 = (const float*)d_in[4];
  const float* W2 = (const float*)d_in[5];
  const float* b2 = (const float*)d_in[6];
  const float* Wd = (const float*)d_in[7];
  const float* bd = (const float*)d_in[8];
  float* out = (float*)d_out;
  char* ws = (char*)d_ws;

  u16*   WbcT  = (u16*)(ws + WS_WBCT);
  u16*   WdT   = (u16*)(ws + WS_WDT);
  u16*   W2T   = (u16*)(ws + WS_W2T);
  float* WdS   = (float*)(ws + WS_WDS);
  float* Wsum  = (float*)(ws + WS_WSUM);
  float* bias1 = (float*)(ws + WS_BIAS1);

  prep_weights<<<dim3(256), dim3(256), 0, stream>>>(W1, W2, Wd, bd, WbcT, WdT, W2T, WdS, Wsum);
  prep_bias<<<dim3(NBATCH), dim3(256), 0, stream>>>(queries, Wsum, b1, bias1);
  seqatt_main<<<dim3(NBATCH), dim3(512), 0, stream>>>(queries, keys, keys_length,
                                                      WbcT, WdT, W2T, WdS, bias1, b2, out);
}